// Round 1
// baseline (4666.293 us; speedup 1.0000x reference)
//
#include <hip/hip_runtime.h>
#include <math.h>

// Problem constants
#define N_NODES 50000
#define N_EDGES 800000
#define IN_CH 128
#define HID 256
#define OUT_CH 40

// ---------------------------------------------------------------------------
// Scatter-add aggregation: agg[dst] += feat[src], float4-vectorized atomics.
// g = global thread id; each thread handles one float4 group of one edge.
// ---------------------------------------------------------------------------
__global__ __launch_bounds__(256) void scatter_add_f4(
    const float* __restrict__ feat, const int* __restrict__ ei,
    float* __restrict__ agg, int nE, int C, int shift)
{
    long long g = (long long)blockIdx.x * blockDim.x + threadIdx.x;
    int e = (int)(g >> shift);
    if (e >= nE) return;
    int c = ((int)g & ((1 << shift) - 1)) << 2;
    int s = ei[e];
    int d = ei[nE + e];
    const float4 v = *(const float4*)(feat + (size_t)s * C + c);
    float* p = agg + (size_t)d * C + c;
    atomicAdd(p + 0, v.x);
    atomicAdd(p + 1, v.y);
    atomicAdd(p + 2, v.z);
    atomicAdd(p + 3, v.w);
}

// ---------------------------------------------------------------------------
// Generic fp32 SGEMM: out[M,N] = act( Aeff[M,K] @ W[K,N] + bias )
//   Aeff[r][k] = (Acat && k >= Ksplit) ? Acat[r][k-Ksplit]
//                                      : A[r][k] (+ Aadd[r][k] if Aadd)
// A/Aadd/Acat all have row stride strideA. W row-major [K,N]. N % 4 == 0.
// Block: 256 threads, BM=128 x BN=128 tile, 8x8 micro-tile per thread,
// split as rows {ty*4..+3, 64+ty*4..+3}, cols {tx*4..+3, 64+tx*4..+3}
// so LDS fragment reads are broadcast / 2-way (free) instead of 4-way.
// ---------------------------------------------------------------------------
#define BM 128
#define BN 128
#define BK 32

__global__ __launch_bounds__(256, 2) void gemm_bias_act(
    const float* __restrict__ A, const float* __restrict__ Aadd,
    const float* __restrict__ Acat, int Ksplit, int strideA,
    const float* __restrict__ W, const float* __restrict__ bias,
    float* __restrict__ out, int M, int N, int K, int doRelu)
{
    __shared__ float As[BK][BM + 4];   // transposed: As[k][m]; stride 132 (16B-aligned rows)
    __shared__ float Bs[BK][BN];

    const int tid = threadIdx.x;
    const int tx = tid & 15;
    const int ty = tid >> 4;
    const int row0 = blockIdx.y * BM;
    const int col0 = blockIdx.x * BN;

    float acc[8][8];
#pragma unroll
    for (int i = 0; i < 8; i++)
#pragma unroll
        for (int j = 0; j < 8; j++) acc[i][j] = 0.f;

    for (int kk = 0; kk < K; kk += BK) {
        // ---- load A tile (BM x BK) into As (transposed) ----
#pragma unroll
        for (int i = 0; i < 4; i++) {
            int f = i * 256 + tid;       // float4 slot 0..1023
            int r = f >> 3;              // tile row 0..127
            int c4 = (f & 7) << 2;       // k offset 0,4,...,28
            int grow = row0 + r;
            float4 v = make_float4(0.f, 0.f, 0.f, 0.f);
            if (grow < M) {
                int kg = kk + c4;
                const float* p = (Acat != nullptr && kg >= Ksplit)
                    ? (Acat + (size_t)grow * strideA + (kg - Ksplit))
                    : (A + (size_t)grow * strideA + kg);
                v = *(const float4*)p;
                if (Aadd != nullptr) {
                    float4 w2 = *(const float4*)(Aadd + (size_t)grow * strideA + kg);
                    v.x += w2.x; v.y += w2.y; v.z += w2.z; v.w += w2.w;
                }
            }
            As[c4 + 0][r] = v.x;
            As[c4 + 1][r] = v.y;
            As[c4 + 2][r] = v.z;
            As[c4 + 3][r] = v.w;
        }
        // ---- load B tile (BK x BN) ----
#pragma unroll
        for (int i = 0; i < 4; i++) {
            int f = i * 256 + tid;
            int r = f >> 5;              // 0..31
            int c4 = (f & 31) << 2;      // 0..124
            int gc = col0 + c4;
            float4 v = make_float4(0.f, 0.f, 0.f, 0.f);
            if (gc < N) v = *(const float4*)(W + (size_t)(kk + r) * N + gc);
            *(float4*)&Bs[r][c4] = v;
        }
        __syncthreads();

#pragma unroll
        for (int k = 0; k < BK; k++) {
            float4 a0 = *(const float4*)&As[k][ty * 4];
            float4 a1 = *(const float4*)&As[k][64 + ty * 4];
            float4 b0 = *(const float4*)&Bs[k][tx * 4];
            float4 b1 = *(const float4*)&Bs[k][64 + tx * 4];
            float a[8] = {a0.x, a0.y, a0.z, a0.w, a1.x, a1.y, a1.z, a1.w};
            float b[8] = {b0.x, b0.y, b0.z, b0.w, b1.x, b1.y, b1.z, b1.w};
#pragma unroll
            for (int i = 0; i < 8; i++)
#pragma unroll
                for (int j = 0; j < 8; j++) acc[i][j] += a[i] * b[j];
        }
        __syncthreads();
    }

    // ---- epilogue: bias + optional relu, guarded float4 stores ----
#pragma unroll
    for (int i = 0; i < 8; i++) {
        int r = row0 + ((i < 4) ? (ty * 4 + i) : (64 + ty * 4 + (i - 4)));
        if (r >= M) continue;
#pragma unroll
        for (int jh = 0; jh < 2; jh++) {
            int c = col0 + jh * 64 + tx * 4;
            if (c >= N) continue;
            float4 o;
            o.x = acc[i][jh * 4 + 0] + bias[c + 0];
            o.y = acc[i][jh * 4 + 1] + bias[c + 1];
            o.z = acc[i][jh * 4 + 2] + bias[c + 2];
            o.w = acc[i][jh * 4 + 3] + bias[c + 3];
            if (doRelu) {
                o.x = fmaxf(o.x, 0.f); o.y = fmaxf(o.y, 0.f);
                o.z = fmaxf(o.z, 0.f); o.w = fmaxf(o.w, 0.f);
            }
            *(float4*)(out + (size_t)r * N + c) = o;
        }
    }
}

// ---------------------------------------------------------------------------
// log_softmax over 40 columns; one wave per row (4 rows / 256-thread block).
// ---------------------------------------------------------------------------
__global__ __launch_bounds__(256) void logsoftmax40(
    const float* __restrict__ L, float* __restrict__ out, int M)
{
    int w = threadIdx.x >> 6;
    int l = threadIdx.x & 63;
    int row = blockIdx.x * 4 + w;
    if (row >= M) return;
    float v = (l < OUT_CH) ? L[(size_t)row * OUT_CH + l] : -INFINITY;
    float m = v;
#pragma unroll
    for (int o = 32; o > 0; o >>= 1) m = fmaxf(m, __shfl_xor(m, o, 64));
    float e = (l < OUT_CH) ? expf(v - m) : 0.f;
    float s = e;
#pragma unroll
    for (int o = 32; o > 0; o >>= 1) s += __shfl_xor(s, o, 64);
    if (l < OUT_CH) out[(size_t)row * OUT_CH + l] = v - m - logf(s);
}

// ---------------------------------------------------------------------------
extern "C" void kernel_launch(void* const* d_in, const int* in_sizes, int n_in,
                              void* d_out, int out_size, void* d_ws, size_t ws_size,
                              hipStream_t stream)
{
    const float* x    = (const float*)d_in[0];
    const int*   ei   = (const int*)d_in[1];
    const float* W1a  = (const float*)d_in[2];
    const float* b1a  = (const float*)d_in[3];
    const float* W2a  = (const float*)d_in[4];
    const float* b2a  = (const float*)d_in[5];
    const float* W1b  = (const float*)d_in[6];
    const float* b1b  = (const float*)d_in[7];
    const float* W2b  = (const float*)d_in[8];
    const float* b2b  = (const float*)d_in[9];
    const float* Wlin = (const float*)d_in[10];
    const float* blin = (const float*)d_in[11];
    float* out = (float*)d_out;

    const size_t bufElems = (size_t)N_NODES * HID;   // 12.8M floats
    float* bufA = (float*)d_ws;                      // agg_a / agg_b / h2
    float* bufB = bufA + bufElems;                   // t1 / t2 / logits
    float* bufC = bufB + bufElems;                   // h1

    dim3 blk(256);
    dim3 gemmGrid2(2, (N_NODES + BM - 1) / BM);      // N=256
    dim3 gemmGrid1(1, (N_NODES + BM - 1) / BM);      // N=40

    // ---- Layer a ----
    hipMemsetAsync(bufA, 0, (size_t)N_NODES * IN_CH * sizeof(float), stream);
    scatter_add_f4<<<(N_EDGES * (IN_CH / 4)) / 256, blk, 0, stream>>>(
        x, ei, bufA, N_EDGES, IN_CH, 5);
    // t1 = relu((x+agg) @ W1a + b1a)
    gemm_bias_act<<<gemmGrid2, blk, 0, stream>>>(
        x, bufA, nullptr, IN_CH, IN_CH, W1a, b1a, bufB, N_NODES, HID, IN_CH, 1);
    // h1 = relu(t1 @ W2a + b2a)
    gemm_bias_act<<<gemmGrid2, blk, 0, stream>>>(
        bufB, nullptr, nullptr, HID, HID, W2a, b2a, bufC, N_NODES, HID, HID, 1);

    // ---- Layer b ----
    hipMemsetAsync(bufA, 0, (size_t)N_NODES * HID * sizeof(float), stream);
    scatter_add_f4<<<(N_EDGES * (HID / 4)) / 256, blk, 0, stream>>>(
        bufC, ei, bufA, N_EDGES, HID, 6);
    // t2 = relu((h1+agg) @ W1b + b1b)
    gemm_bias_act<<<gemmGrid2, blk, 0, stream>>>(
        bufC, bufA, nullptr, HID, HID, W1b, b1b, bufB, N_NODES, HID, HID, 1);
    // h2 = relu(t2 @ W2b + b2b)  -> bufA (agg_b no longer needed)
    gemm_bias_act<<<gemmGrid2, blk, 0, stream>>>(
        bufB, nullptr, nullptr, HID, HID, W2b, b2b, bufA, N_NODES, HID, HID, 1);

    // ---- Final linear on [h1 | h2] then log_softmax ----
    gemm_bias_act<<<gemmGrid1, blk, 0, stream>>>(
        bufC, nullptr, bufA, HID, HID, Wlin, blin, bufB, N_NODES, OUT_CH, 2 * HID, 0);
    logsoftmax40<<<(N_NODES + 3) / 4, blk, 0, stream>>>(bufB, out, N_NODES);
}

// Round 2
// 876.447 us; speedup vs baseline: 5.3241x; 5.3241x over previous
//
#include <hip/hip_runtime.h>
#include <math.h>

// Problem constants
#define N_NODES 50000
#define N_EDGES 800000
#define IN_CH 128
#define HID 256
#define OUT_CH 40

// ===========================================================================
// CSR build: degree histogram -> exclusive scan -> bucket fill
// ===========================================================================
__global__ __launch_bounds__(256) void deg_count(
    const int* __restrict__ ei, int* __restrict__ deg)
{
    int e = blockIdx.x * 256 + threadIdx.x;
    if (e < N_EDGES) atomicAdd(&deg[ei[N_EDGES + e]], 1);
}

// scan1: each block scans 1024 elements (256 thr x 4), writes local exclusive
// prefix into excl[] and its block total into partials[blockIdx.x].
__global__ __launch_bounds__(256) void scan1(
    const int* __restrict__ deg, int* __restrict__ excl, int* __restrict__ partials)
{
    __shared__ int lds[256];
    const int tid = threadIdx.x;
    const int base = blockIdx.x * 1024 + tid * 4;
    int v[4]; int s = 0;
#pragma unroll
    for (int i = 0; i < 4; i++) {
        int idx = base + i;
        v[i] = (idx < N_NODES) ? deg[idx] : 0;
        s += v[i];
    }
    lds[tid] = s;
    __syncthreads();
    // inclusive scan of thread sums (Hillis-Steele)
    for (int off = 1; off < 256; off <<= 1) {
        int t = (tid >= off) ? lds[tid - off] : 0;
        __syncthreads();
        lds[tid] += t;
        __syncthreads();
    }
    int texcl = lds[tid] - s;            // exclusive offset of this thread
    int run = texcl;
#pragma unroll
    for (int i = 0; i < 4; i++) {
        int idx = base + i;
        if (idx < N_NODES) excl[idx] = run;
        run += v[i];
    }
    if (tid == 255) partials[blockIdx.x] = lds[255];
}

// scan2: exclusive scan of the (<=64) block partials in a single wave.
__global__ __launch_bounds__(64) void scan2(int* __restrict__ partials, int n)
{
    int l = threadIdx.x;
    int orig = (l < n) ? partials[l] : 0;
    int v = orig;
#pragma unroll
    for (int off = 1; off < 64; off <<= 1) {
        int t = __shfl_up(v, off, 64);
        if (l >= off) v += t;
    }
    if (l < n) partials[l] = v - orig;    // exclusive
}

// scan3: add block offsets; produce row_ptr (=start) and cursor copy.
__global__ __launch_bounds__(256) void scan3(
    int* __restrict__ excl, const int* __restrict__ partials, int* __restrict__ cursor)
{
    int idx = blockIdx.x * 256 + threadIdx.x;
    if (idx < N_NODES) {
        int r = excl[idx] + partials[idx >> 10];
        excl[idx] = r;
        cursor[idx] = r;
    }
}

// fill: scatter edge source ids into CSR buckets (cursor ends at row end).
__global__ __launch_bounds__(256) void csr_fill(
    const int* __restrict__ ei, int* __restrict__ cursor, int* __restrict__ csr_src)
{
    int e = blockIdx.x * 256 + threadIdx.x;
    if (e < N_EDGES) {
        int s = ei[e];
        int d = ei[N_EDGES + e];
        int pos = atomicAdd(&cursor[d], 1);
        csr_src[pos] = s;
    }
}

// ===========================================================================
// Gather aggregation: out[n] = feat[n] + sum_{e in CSR row n} feat[src[e]]
// One 64-lane wave per node. After csr_fill, cursor[n] == row end.
// ===========================================================================
__global__ __launch_bounds__(256) void gather_agg128(
    const float* __restrict__ feat, const int* __restrict__ row_ptr,
    const int* __restrict__ row_end, const int* __restrict__ csr_src,
    float* __restrict__ out)
{
    int node = (blockIdx.x * 256 + threadIdx.x) >> 6;
    int lane = threadIdx.x & 63;
    if (node >= N_NODES) return;
    const int coff = lane * 2;
    float2 acc = *(const float2*)(feat + (size_t)node * IN_CH + coff);
    int j = row_ptr[node], e = row_end[node];
    for (; j + 1 < e; j += 2) {
        int sa = csr_src[j], sb = csr_src[j + 1];
        float2 va = *(const float2*)(feat + (size_t)sa * IN_CH + coff);
        float2 vb = *(const float2*)(feat + (size_t)sb * IN_CH + coff);
        acc.x += va.x + vb.x;
        acc.y += va.y + vb.y;
    }
    if (j < e) {
        int sa = csr_src[j];
        float2 va = *(const float2*)(feat + (size_t)sa * IN_CH + coff);
        acc.x += va.x; acc.y += va.y;
    }
    *(float2*)(out + (size_t)node * IN_CH + coff) = acc;
}

__global__ __launch_bounds__(256) void gather_agg256(
    const float* __restrict__ feat, const int* __restrict__ row_ptr,
    const int* __restrict__ row_end, const int* __restrict__ csr_src,
    float* __restrict__ out)
{
    int node = (blockIdx.x * 256 + threadIdx.x) >> 6;
    int lane = threadIdx.x & 63;
    if (node >= N_NODES) return;
    const int coff = lane * 4;
    float4 acc = *(const float4*)(feat + (size_t)node * HID + coff);
    int j = row_ptr[node], e = row_end[node];
    for (; j + 1 < e; j += 2) {
        int sa = csr_src[j], sb = csr_src[j + 1];
        float4 va = *(const float4*)(feat + (size_t)sa * HID + coff);
        float4 vb = *(const float4*)(feat + (size_t)sb * HID + coff);
        acc.x += va.x + vb.x; acc.y += va.y + vb.y;
        acc.z += va.z + vb.z; acc.w += va.w + vb.w;
    }
    if (j < e) {
        int sa = csr_src[j];
        float4 va = *(const float4*)(feat + (size_t)sa * HID + coff);
        acc.x += va.x; acc.y += va.y; acc.z += va.z; acc.w += va.w;
    }
    *(float4*)(out + (size_t)node * HID + coff) = acc;
}

// ===========================================================================
// Generic fp32 SGEMM: out[M,N] = act( Aeff[M,K] @ W[K,N] + bias )
//   Aeff[r][k] = (Acat && k >= Ksplit) ? Acat[r][k-Ksplit] : A[r][k]
// ===========================================================================
#define BM 128
#define BN 128
#define BK 32

__global__ __launch_bounds__(256, 2) void gemm_bias_act(
    const float* __restrict__ A,
    const float* __restrict__ Acat, int Ksplit, int strideA,
    const float* __restrict__ W, const float* __restrict__ bias,
    float* __restrict__ out, int M, int N, int K, int doRelu)
{
    __shared__ float As[BK][BM + 4];
    __shared__ float Bs[BK][BN];

    const int tid = threadIdx.x;
    const int tx = tid & 15;
    const int ty = tid >> 4;
    const int row0 = blockIdx.y * BM;
    const int col0 = blockIdx.x * BN;

    float acc[8][8];
#pragma unroll
    for (int i = 0; i < 8; i++)
#pragma unroll
        for (int j = 0; j < 8; j++) acc[i][j] = 0.f;

    for (int kk = 0; kk < K; kk += BK) {
#pragma unroll
        for (int i = 0; i < 4; i++) {
            int f = i * 256 + tid;
            int r = f >> 3;
            int c4 = (f & 7) << 2;
            int grow = row0 + r;
            float4 v = make_float4(0.f, 0.f, 0.f, 0.f);
            if (grow < M) {
                int kg = kk + c4;
                const float* p = (Acat != nullptr && kg >= Ksplit)
                    ? (Acat + (size_t)grow * strideA + (kg - Ksplit))
                    : (A + (size_t)grow * strideA + kg);
                v = *(const float4*)p;
            }
            As[c4 + 0][r] = v.x;
            As[c4 + 1][r] = v.y;
            As[c4 + 2][r] = v.z;
            As[c4 + 3][r] = v.w;
        }
#pragma unroll
        for (int i = 0; i < 4; i++) {
            int f = i * 256 + tid;
            int r = f >> 5;
            int c4 = (f & 31) << 2;
            int gc = col0 + c4;
            float4 v = make_float4(0.f, 0.f, 0.f, 0.f);
            if (gc < N) v = *(const float4*)(W + (size_t)(kk + r) * N + gc);
            *(float4*)&Bs[r][c4] = v;
        }
        __syncthreads();

#pragma unroll
        for (int k = 0; k < BK; k++) {
            float4 a0 = *(const float4*)&As[k][ty * 4];
            float4 a1 = *(const float4*)&As[k][64 + ty * 4];
            float4 b0 = *(const float4*)&Bs[k][tx * 4];
            float4 b1 = *(const float4*)&Bs[k][64 + tx * 4];
            float a[8] = {a0.x, a0.y, a0.z, a0.w, a1.x, a1.y, a1.z, a1.w};
            float b[8] = {b0.x, b0.y, b0.z, b0.w, b1.x, b1.y, b1.z, b1.w};
#pragma unroll
            for (int i = 0; i < 8; i++)
#pragma unroll
                for (int j = 0; j < 8; j++) acc[i][j] += a[i] * b[j];
        }
        __syncthreads();
    }

#pragma unroll
    for (int i = 0; i < 8; i++) {
        int r = row0 + ((i < 4) ? (ty * 4 + i) : (64 + ty * 4 + (i - 4)));
        if (r >= M) continue;
#pragma unroll
        for (int jh = 0; jh < 2; jh++) {
            int c = col0 + jh * 64 + tx * 4;
            if (c >= N) continue;
            float4 o;
            o.x = acc[i][jh * 4 + 0] + bias[c + 0];
            o.y = acc[i][jh * 4 + 1] + bias[c + 1];
            o.z = acc[i][jh * 4 + 2] + bias[c + 2];
            o.w = acc[i][jh * 4 + 3] + bias[c + 3];
            if (doRelu) {
                o.x = fmaxf(o.x, 0.f); o.y = fmaxf(o.y, 0.f);
                o.z = fmaxf(o.z, 0.f); o.w = fmaxf(o.w, 0.f);
            }
            *(float4*)(out + (size_t)r * N + c) = o;
        }
    }
}

// ---------------------------------------------------------------------------
// log_softmax over 40 columns; one wave per row.
// ---------------------------------------------------------------------------
__global__ __launch_bounds__(256) void logsoftmax40(
    const float* __restrict__ L, float* __restrict__ out, int M)
{
    int w = threadIdx.x >> 6;
    int l = threadIdx.x & 63;
    int row = blockIdx.x * 4 + w;
    if (row >= M) return;
    float v = (l < OUT_CH) ? L[(size_t)row * OUT_CH + l] : -INFINITY;
    float m = v;
#pragma unroll
    for (int o = 32; o > 0; o >>= 1) m = fmaxf(m, __shfl_xor(m, o, 64));
    float e = (l < OUT_CH) ? expf(v - m) : 0.f;
    float s = e;
#pragma unroll
    for (int o = 32; o > 0; o >>= 1) s += __shfl_xor(s, o, 64);
    if (l < OUT_CH) out[(size_t)row * OUT_CH + l] = v - m - logf(s);
}

// ---------------------------------------------------------------------------
extern "C" void kernel_launch(void* const* d_in, const int* in_sizes, int n_in,
                              void* d_out, int out_size, void* d_ws, size_t ws_size,
                              hipStream_t stream)
{
    const float* x    = (const float*)d_in[0];
    const int*   ei   = (const int*)d_in[1];
    const float* W1a  = (const float*)d_in[2];
    const float* b1a  = (const float*)d_in[3];
    const float* W2a  = (const float*)d_in[4];
    const float* b2a  = (const float*)d_in[5];
    const float* W1b  = (const float*)d_in[6];
    const float* b1b  = (const float*)d_in[7];
    const float* W2b  = (const float*)d_in[8];
    const float* b2b  = (const float*)d_in[9];
    const float* Wlin = (const float*)d_in[10];
    const float* blin = (const float*)d_in[11];
    float* out = (float*)d_out;

    const size_t bufElems = (size_t)N_NODES * HID;   // 12.8M floats
    float* bufA = (float*)d_ws;                      // agg_a / agg_b / h2
    float* bufB = bufA + bufElems;                   // t1 / t2 / logits
    float* bufC = bufB + bufElems;                   // h1
    int* deg    = (int*)(bufC + bufElems);           // [N_NODES]
    int* rowp   = deg + N_NODES;                     // [N_NODES] row starts
    int* cursor = rowp + N_NODES;                    // [N_NODES] -> row ends
    int* part   = cursor + N_NODES;                  // [64]
    int* csr    = part + 64;                         // [N_EDGES]

    dim3 blk(256);
    dim3 gemmGrid2(2, (N_NODES + BM - 1) / BM);      // N=256
    dim3 gemmGrid1(1, (N_NODES + BM - 1) / BM);      // N=40
    const int scanBlocks = (N_NODES + 1023) / 1024;  // 49
    const int edgeBlocks = (N_EDGES + 255) / 256;
    const int aggBlocks  = (N_NODES + 3) / 4;        // 4 waves/block

    // ---- CSR build (once; reused by both layers) ----
    hipMemsetAsync(deg, 0, N_NODES * sizeof(int), stream);
    deg_count<<<edgeBlocks, blk, 0, stream>>>(ei, deg);
    scan1<<<scanBlocks, blk, 0, stream>>>(deg, rowp, part);
    scan2<<<1, 64, 0, stream>>>(part, scanBlocks);
    scan3<<<(N_NODES + 255) / 256, blk, 0, stream>>>(rowp, part, cursor);
    csr_fill<<<edgeBlocks, blk, 0, stream>>>(ei, cursor, csr);

    // ---- Layer a ----
    gather_agg128<<<aggBlocks, blk, 0, stream>>>(x, rowp, cursor, csr, bufA);
    gemm_bias_act<<<gemmGrid2, blk, 0, stream>>>(
        bufA, nullptr, IN_CH, IN_CH, W1a, b1a, bufB, N_NODES, HID, IN_CH, 1);
    gemm_bias_act<<<gemmGrid2, blk, 0, stream>>>(
        bufB, nullptr, HID, HID, W2a, b2a, bufC, N_NODES, HID, HID, 1);

    // ---- Layer b ----
    gather_agg256<<<aggBlocks, blk, 0, stream>>>(bufC, rowp, cursor, csr, bufA);
    gemm_bias_act<<<gemmGrid2, blk, 0, stream>>>(
        bufA, nullptr, HID, HID, W1b, b1b, bufB, N_NODES, HID, HID, 1);
    gemm_bias_act<<<gemmGrid2, blk, 0, stream>>>(
        bufB, nullptr, HID, HID, W2b, b2b, bufA, N_NODES, HID, HID, 1);

    // ---- Final linear on [h1 | h2] then log_softmax ----
    gemm_bias_act<<<gemmGrid1, blk, 0, stream>>>(
        bufC, bufA, HID, HID, Wlin, blin, bufB, N_NODES, OUT_CH, 2 * HID, 0);
    logsoftmax40<<<(N_NODES + 3) / 4, blk, 0, stream>>>(bufB, out, N_NODES);
}

// Round 3
// 441.714 us; speedup vs baseline: 10.5641x; 1.9842x over previous
//
#include <hip/hip_runtime.h>
#include <math.h>

// Problem constants
#define N_NODES 50000
#define N_EDGES 800000
#define IN_CH 128
#define HID 256
#define OUT_CH 40

typedef unsigned short u16;
typedef __attribute__((ext_vector_type(8))) short bf16x8;
typedef __attribute__((ext_vector_type(4))) float f32x4;

__device__ __forceinline__ float bf2f(u16 u) {
    union { unsigned int i; float f; } v; v.i = ((unsigned int)u) << 16; return v.f;
}
__device__ __forceinline__ u16 f2bf(float f) {   // round-to-nearest-even
    union { float f; unsigned int i; } v; v.f = f;
    unsigned int x = v.i;
    x += 0x7fffu + ((x >> 16) & 1u);
    return (u16)(x >> 16);
}

#define GLOBAL_AS __attribute__((address_space(1)))
#define LDS_AS __attribute__((address_space(3)))
__device__ __forceinline__ void async_cp16(const void* g, void* l) {
    __builtin_amdgcn_global_load_lds((const GLOBAL_AS unsigned int*)g,
                                     (LDS_AS unsigned int*)l, 16, 0, 0);
}

// ===========================================================================
// CSR build: degree histogram -> exclusive scan -> bucket fill
// ===========================================================================
__global__ __launch_bounds__(256) void deg_count(
    const int* __restrict__ ei, int* __restrict__ deg)
{
    int e = blockIdx.x * 256 + threadIdx.x;
    if (e < N_EDGES) atomicAdd(&deg[ei[N_EDGES + e]], 1);
}

__global__ __launch_bounds__(256) void scan1(
    const int* __restrict__ deg, int* __restrict__ excl, int* __restrict__ partials)
{
    __shared__ int lds[256];
    const int tid = threadIdx.x;
    const int base = blockIdx.x * 1024 + tid * 4;
    int v[4]; int s = 0;
#pragma unroll
    for (int i = 0; i < 4; i++) {
        int idx = base + i;
        v[i] = (idx < N_NODES) ? deg[idx] : 0;
        s += v[i];
    }
    lds[tid] = s;
    __syncthreads();
    for (int off = 1; off < 256; off <<= 1) {
        int t = (tid >= off) ? lds[tid - off] : 0;
        __syncthreads();
        lds[tid] += t;
        __syncthreads();
    }
    int run = lds[tid] - s;
#pragma unroll
    for (int i = 0; i < 4; i++) {
        int idx = base + i;
        if (idx < N_NODES) excl[idx] = run;
        run += v[i];
    }
    if (tid == 255) partials[blockIdx.x] = lds[255];
}

__global__ __launch_bounds__(64) void scan2(int* __restrict__ partials, int n)
{
    int l = threadIdx.x;
    int orig = (l < n) ? partials[l] : 0;
    int v = orig;
#pragma unroll
    for (int off = 1; off < 64; off <<= 1) {
        int t = __shfl_up(v, off, 64);
        if (l >= off) v += t;
    }
    if (l < n) partials[l] = v - orig;
}

__global__ __launch_bounds__(256) void scan3(
    int* __restrict__ excl, const int* __restrict__ partials, int* __restrict__ cursor)
{
    int idx = blockIdx.x * 256 + threadIdx.x;
    if (idx < N_NODES) {
        int r = excl[idx] + partials[idx >> 10];
        excl[idx] = r;
        cursor[idx] = r;
    }
}

__global__ __launch_bounds__(256) void csr_fill(
    const int* __restrict__ ei, int* __restrict__ cursor, int* __restrict__ csr_src)
{
    int e = blockIdx.x * 256 + threadIdx.x;
    if (e < N_EDGES) {
        int s = ei[e];
        int d = ei[N_EDGES + e];
        int pos = atomicAdd(&cursor[d], 1);
        csr_src[pos] = s;
    }
}

// ===========================================================================
// Conversions
// ===========================================================================
// x fp32 -> bf16, 4 elems/thread (6.4M elems total)
__global__ __launch_bounds__(256) void conv_x_bf(
    const float* __restrict__ x, u16* __restrict__ xb)
{
    int i = blockIdx.x * 256 + threadIdx.x;       // float4 index
    float4 v = ((const float4*)x)[i];
    ushort4 o;
    o.x = f2bf(v.x); o.y = f2bf(v.y); o.z = f2bf(v.z); o.w = f2bf(v.w);
    ((ushort4*)xb)[i] = o;
}

// W fp32 [K,N] -> bf16 W^T [Npad,K], zero rows for n >= N. grid.x = Npad.
__global__ __launch_bounds__(256) void transpose_w(
    const float* __restrict__ in, u16* __restrict__ out, int K, int N)
{
    int n = blockIdx.x;
    for (int k = threadIdx.x; k < K; k += 256) {
        float v = (n < N) ? in[(size_t)k * N + n] : 0.f;
        out[(size_t)n * K + k] = f2bf(v);
    }
}

// ===========================================================================
// Gather aggregation (bf16 in/out, fp32 accumulate):
//   out[n] = feat[n] + sum_{e in CSR row n} feat[src[e]]
// One 64-lane wave per node.
// ===========================================================================
__global__ __launch_bounds__(256) void gather_agg_bf128(
    const u16* __restrict__ feat, const int* __restrict__ row_ptr,
    const int* __restrict__ row_end, const int* __restrict__ csr_src,
    u16* __restrict__ out)
{
    int node = (blockIdx.x * 256 + threadIdx.x) >> 6;
    int lane = threadIdx.x & 63;
    if (node >= N_NODES) return;
    ushort2 sv = ((const ushort2*)(feat + (size_t)node * IN_CH))[lane];
    float ax = bf2f(sv.x), ay = bf2f(sv.y);
    int j = row_ptr[node], e = row_end[node];
    for (; j + 1 < e; j += 2) {
        int sa = csr_src[j], sb = csr_src[j + 1];
        ushort2 va = ((const ushort2*)(feat + (size_t)sa * IN_CH))[lane];
        ushort2 vb = ((const ushort2*)(feat + (size_t)sb * IN_CH))[lane];
        ax += bf2f(va.x) + bf2f(vb.x);
        ay += bf2f(va.y) + bf2f(vb.y);
    }
    if (j < e) {
        int sa = csr_src[j];
        ushort2 va = ((const ushort2*)(feat + (size_t)sa * IN_CH))[lane];
        ax += bf2f(va.x); ay += bf2f(va.y);
    }
    ushort2 o; o.x = f2bf(ax); o.y = f2bf(ay);
    ((ushort2*)(out + (size_t)node * IN_CH))[lane] = o;
}

__global__ __launch_bounds__(256) void gather_agg_bf256(
    const u16* __restrict__ feat, const int* __restrict__ row_ptr,
    const int* __restrict__ row_end, const int* __restrict__ csr_src,
    u16* __restrict__ out)
{
    int node = (blockIdx.x * 256 + threadIdx.x) >> 6;
    int lane = threadIdx.x & 63;
    if (node >= N_NODES) return;
    ushort4 sv = ((const ushort4*)(feat + (size_t)node * HID))[lane];
    float ax = bf2f(sv.x), ay = bf2f(sv.y), az = bf2f(sv.z), aw = bf2f(sv.w);
    int j = row_ptr[node], e = row_end[node];
    for (; j + 1 < e; j += 2) {
        int sa = csr_src[j], sb = csr_src[j + 1];
        ushort4 va = ((const ushort4*)(feat + (size_t)sa * HID))[lane];
        ushort4 vb = ((const ushort4*)(feat + (size_t)sb * HID))[lane];
        ax += bf2f(va.x) + bf2f(vb.x);
        ay += bf2f(va.y) + bf2f(vb.y);
        az += bf2f(va.z) + bf2f(vb.z);
        aw += bf2f(va.w) + bf2f(vb.w);
    }
    if (j < e) {
        int sa = csr_src[j];
        ushort4 va = ((const ushort4*)(feat + (size_t)sa * HID))[lane];
        ax += bf2f(va.x); ay += bf2f(va.y); az += bf2f(va.z); aw += bf2f(va.w);
    }
    ushort4 o;
    o.x = f2bf(ax); o.y = f2bf(ay); o.z = f2bf(az); o.w = f2bf(aw);
    ((ushort4*)(out + (size_t)node * HID))[lane] = o;
}

// ===========================================================================
// bf16 MFMA GEMM (m97 structure): out = act(Aeff[M,K] @ BT^T + bias)
//   Aeff rows: A (k < Ksplit) / Acat (k >= Ksplit), both with row stride ldA.
//   BT is [Npad, K] bf16 row-major (pre-transposed weights), Npad = 128*gridDim.x.
//   128x128 block tile, BK=32, 4 waves each computing 64x64 via 4x4 MFMA tiles.
// Fragment layouts (verified m89/m91): A[m=lane&15][k=(lane>>4)*8+j],
//   B[k=(lane>>4)*8+j][n=lane&15], C/D: col=lane&15, row=(lane>>4)*4+reg.
// ===========================================================================
__global__ __launch_bounds__(256, 2) void gemm_mfma(
    const u16* __restrict__ A, const u16* __restrict__ Acat, int Ksplit, int ldA,
    const u16* __restrict__ BT, const float* __restrict__ bias,
    void* __restrict__ out, int outBf16, int M, int Nreal, int K, int relu, int ldOut)
{
    __shared__ u16 As[128 * 32];   // [row][k] 64B rows, no pad (global_load_lds)
    __shared__ u16 Bs[128 * 32];   // [n][k]

    const int tid = threadIdx.x;
    const int lane = tid & 63;
    const int wid = tid >> 6;
    const int wm = wid >> 1, wn = wid & 1;
    const int row0 = blockIdx.y * 128;
    const int col0 = blockIdx.x * 128;

    f32x4 acc[4][4];
#pragma unroll
    for (int i = 0; i < 4; i++)
#pragma unroll
        for (int j = 0; j < 4; j++) acc[i][j] = (f32x4){0.f, 0.f, 0.f, 0.f};

    for (int kk = 0; kk < K; kk += 32) {
        const u16* Abase = (Acat != nullptr && kk >= Ksplit) ? Acat : A;
        const int kbase = (Acat != nullptr && kk >= Ksplit) ? (kk - Ksplit) : kk;
        // ---- stage A tile: 128 rows x 32 k = 512 16B-chunks ----
#pragma unroll
        for (int i = 0; i < 2; i++) {
            int chunk = i * 256 + tid;
            int r = chunk >> 2, c = chunk & 3;
            int grow = row0 + r; if (grow > M - 1) grow = M - 1;
            async_cp16(Abase + (size_t)grow * ldA + kbase + c * 8, As + chunk * 8);
        }
        // ---- stage B tile ----
#pragma unroll
        for (int i = 0; i < 2; i++) {
            int chunk = i * 256 + tid;
            int r = chunk >> 2, c = chunk & 3;
            async_cp16(BT + (size_t)(col0 + r) * K + kk + c * 8, Bs + chunk * 8);
        }
        __syncthreads();   // drains vmcnt before any wave reads LDS

        const int koff = (lane >> 4) * 8;
        const int am = wm * 64 + (lane & 15);
        const int bn = wn * 64 + (lane & 15);
        bf16x8 af[4], bfr[4];
#pragma unroll
        for (int t = 0; t < 4; t++) {
            af[t]  = *(const bf16x8*)(As + (am + t * 16) * 32 + koff);
            bfr[t] = *(const bf16x8*)(Bs + (bn + t * 16) * 32 + koff);
        }
#pragma unroll
        for (int mt = 0; mt < 4; mt++)
#pragma unroll
            for (int nt = 0; nt < 4; nt++)
                acc[mt][nt] = __builtin_amdgcn_mfma_f32_16x16x32_bf16(
                    af[mt], bfr[nt], acc[mt][nt], 0, 0, 0);
        __syncthreads();   // before next iter overwrites LDS
    }

    // ---- epilogue ----
#pragma unroll
    for (int nt = 0; nt < 4; nt++) {
        int col = col0 + wn * 64 + nt * 16 + (lane & 15);
        bool colOk = (col < Nreal);
        float bv = colOk ? bias[col] : 0.f;
#pragma unroll
        for (int mt = 0; mt < 4; mt++) {
            int rbase = row0 + wm * 64 + mt * 16 + ((lane >> 4) << 2);
#pragma unroll
            for (int reg = 0; reg < 4; reg++) {
                int row = rbase + reg;
                if (colOk && row < M) {
                    float v = acc[mt][nt][reg] + bv;
                    if (relu) v = fmaxf(v, 0.f);
                    if (outBf16)
                        ((u16*)out)[(size_t)row * ldOut + col] = f2bf(v);
                    else
                        ((float*)out)[(size_t)row * ldOut + col] = v;
                }
            }
        }
    }
}

// ---------------------------------------------------------------------------
// log_softmax over 40 columns; one wave per row.
// ---------------------------------------------------------------------------
__global__ __launch_bounds__(256) void logsoftmax40(
    const float* __restrict__ L, float* __restrict__ out, int M)
{
    int w = threadIdx.x >> 6;
    int l = threadIdx.x & 63;
    int row = blockIdx.x * 4 + w;
    if (row >= M) return;
    float v = (l < OUT_CH) ? L[(size_t)row * OUT_CH + l] : -INFINITY;
    float m = v;
#pragma unroll
    for (int o = 32; o > 0; o >>= 1) m = fmaxf(m, __shfl_xor(m, o, 64));
    float e = (l < OUT_CH) ? expf(v - m) : 0.f;
    float s = e;
#pragma unroll
    for (int o = 32; o > 0; o >>= 1) s += __shfl_xor(s, o, 64);
    if (l < OUT_CH) out[(size_t)row * OUT_CH + l] = v - m - logf(s);
}

// ---------------------------------------------------------------------------
extern "C" void kernel_launch(void* const* d_in, const int* in_sizes, int n_in,
                              void* d_out, int out_size, void* d_ws, size_t ws_size,
                              hipStream_t stream)
{
    const float* x    = (const float*)d_in[0];
    const int*   ei   = (const int*)d_in[1];
    const float* W1a  = (const float*)d_in[2];
    const float* b1a  = (const float*)d_in[3];
    const float* W2a  = (const float*)d_in[4];
    const float* b2a  = (const float*)d_in[5];
    const float* W1b  = (const float*)d_in[6];
    const float* b1b  = (const float*)d_in[7];
    const float* W2b  = (const float*)d_in[8];
    const float* b2b  = (const float*)d_in[9];
    const float* Wlin = (const float*)d_in[10];
    const float* blin = (const float*)d_in[11];
    float* out = (float*)d_out;

    // ---- workspace carve-up (regions of 50000*256 bf16 = 25.6 MB) ----
    const size_t R = (size_t)N_NODES * HID;          // elems per region
    u16* R0 = (u16*)d_ws;          // x_bf (first half) -> t2
    u16* R1 = R0 + R;              // zA (first half)   -> logits (fp32, 8MB)
    u16* R2 = R1 + R;              // t1 -> h2
    u16* R3 = R2 + R;              // h1 (live to end)
    u16* R4 = R3 + R;              // zB
    u16* xbf = R0;
    u16* zA  = R1;
    u16* t1  = R2;
    u16* h1  = R3;
    u16* zB  = R4;
    u16* t2  = R0;
    u16* h2  = R2;
    float* logits = (float*)R1;

    u16* wts = R4 + R;             // transposed bf16 weights
    u16* W1aT = wts;                       // [256,128]
    u16* W2aT = W1aT + 256 * 128;          // [256,256]
    u16* W1bT = W2aT + 256 * 256;
    u16* W2bT = W1bT + 256 * 256;
    u16* WlinT = W2bT + 256 * 256;         // [128,512] (rows 40..127 zero)
    int* deg    = (int*)(WlinT + 128 * 512);
    int* rowp   = deg + N_NODES;
    int* cursor = rowp + N_NODES;
    int* part   = cursor + N_NODES;
    int* csr    = part + 64;               // [N_EDGES]

    dim3 blk(256);
    const int scanBlocks = (N_NODES + 1023) / 1024;  // 49
    const int edgeBlocks = (N_EDGES + 255) / 256;
    const int aggBlocks  = (N_NODES + 3) / 4;
    dim3 g2(2, (N_NODES + 127) / 128);               // N=256 GEMMs
    dim3 g1(1, (N_NODES + 127) / 128);               // final GEMM (Npad=128)

    // ---- CSR build ----
    hipMemsetAsync(deg, 0, N_NODES * sizeof(int), stream);
    deg_count<<<edgeBlocks, blk, 0, stream>>>(ei, deg);
    scan1<<<scanBlocks, blk, 0, stream>>>(deg, rowp, part);
    scan2<<<1, 64, 0, stream>>>(part, scanBlocks);
    scan3<<<(N_NODES + 255) / 256, blk, 0, stream>>>(rowp, part, cursor);
    csr_fill<<<edgeBlocks, blk, 0, stream>>>(ei, cursor, csr);

    // ---- conversions ----
    conv_x_bf<<<(N_NODES * IN_CH / 4 + 255) / 256, blk, 0, stream>>>(x, xbf);
    transpose_w<<<256, blk, 0, stream>>>(W1a, W1aT, IN_CH, HID);
    transpose_w<<<256, blk, 0, stream>>>(W2a, W2aT, HID, HID);
    transpose_w<<<256, blk, 0, stream>>>(W1b, W1bT, HID, HID);
    transpose_w<<<256, blk, 0, stream>>>(W2b, W2bT, HID, HID);
    transpose_w<<<128, blk, 0, stream>>>(Wlin, WlinT, 2 * HID, OUT_CH);

    // ---- Layer a ----
    gather_agg_bf128<<<aggBlocks, blk, 0, stream>>>(xbf, rowp, cursor, csr, zA);
    gemm_mfma<<<g2, blk, 0, stream>>>(zA, nullptr, 0, IN_CH, W1aT, b1a,
                                      t1, 1, N_NODES, HID, IN_CH, 1, HID);
    gemm_mfma<<<g2, blk, 0, stream>>>(t1, nullptr, 0, HID, W2aT, b2a,
                                      h1, 1, N_NODES, HID, HID, 1, HID);

    // ---- Layer b ----
    gather_agg_bf256<<<aggBlocks, blk, 0, stream>>>(h1, rowp, cursor, csr, zB);
    gemm_mfma<<<g2, blk, 0, stream>>>(zB, nullptr, 0, HID, W1bT, b1b,
                                      t2, 1, N_NODES, HID, HID, 1, HID);
    gemm_mfma<<<g2, blk, 0, stream>>>(t2, nullptr, 0, HID, W2bT, b2b,
                                      h2, 1, N_NODES, HID, HID, 1, HID);

    // ---- Final linear on [h1 | h2], fp32 logits ----
    gemm_mfma<<<g1, blk, 0, stream>>>(h1, h2, HID, HID, WlinT, blin,
                                      logits, 0, N_NODES, OUT_CH, 2 * HID, 0, OUT_CH);
    logsoftmax40<<<(N_NODES + 3) / 4, blk, 0, stream>>>(logits, out, N_NODES);
}

// Round 4
// 403.347 us; speedup vs baseline: 11.5689x; 1.0951x over previous
//
#include <hip/hip_runtime.h>
#include <math.h>

// Problem constants
#define N_NODES 50000
#define N_EDGES 800000
#define IN_CH 128
#define HID 256
#define OUT_CH 40

typedef unsigned short u16;
typedef __attribute__((ext_vector_type(8))) short bf16x8;
typedef __attribute__((ext_vector_type(4))) float f32x4;

__device__ __forceinline__ float bf2f(u16 u) {
    union { unsigned int i; float f; } v; v.i = ((unsigned int)u) << 16; return v.f;
}
__device__ __forceinline__ u16 f2bf(float f) {   // round-to-nearest-even
    union { float f; unsigned int i; } v; v.f = f;
    unsigned int x = v.i;
    x += 0x7fffu + ((x >> 16) & 1u);
    return (u16)(x >> 16);
}

#define GLOBAL_AS __attribute__((address_space(1)))
#define LDS_AS __attribute__((address_space(3)))
__device__ __forceinline__ void async_cp16(const void* g, void* l) {
    __builtin_amdgcn_global_load_lds((const GLOBAL_AS unsigned int*)g,
                                     (LDS_AS unsigned int*)l, 16, 0, 0);
}

// ===========================================================================
// CSR build: degree histogram -> exclusive scan -> bucket fill
// ===========================================================================
__global__ __launch_bounds__(256) void deg_count(
    const int* __restrict__ ei, int* __restrict__ deg)
{
    int e = blockIdx.x * 256 + threadIdx.x;
    if (e < N_EDGES) atomicAdd(&deg[ei[N_EDGES + e]], 1);
}

__global__ __launch_bounds__(256) void scan1(
    const int* __restrict__ deg, int* __restrict__ excl, int* __restrict__ partials)
{
    __shared__ int lds[256];
    const int tid = threadIdx.x;
    const int base = blockIdx.x * 1024 + tid * 4;
    int v[4]; int s = 0;
#pragma unroll
    for (int i = 0; i < 4; i++) {
        int idx = base + i;
        v[i] = (idx < N_NODES) ? deg[idx] : 0;
        s += v[i];
    }
    lds[tid] = s;
    __syncthreads();
    for (int off = 1; off < 256; off <<= 1) {
        int t = (tid >= off) ? lds[tid - off] : 0;
        __syncthreads();
        lds[tid] += t;
        __syncthreads();
    }
    int run = lds[tid] - s;
#pragma unroll
    for (int i = 0; i < 4; i++) {
        int idx = base + i;
        if (idx < N_NODES) excl[idx] = run;
        run += v[i];
    }
    if (tid == 255) partials[blockIdx.x] = lds[255];
}

__global__ __launch_bounds__(64) void scan2(int* __restrict__ partials, int n)
{
    int l = threadIdx.x;
    int orig = (l < n) ? partials[l] : 0;
    int v = orig;
#pragma unroll
    for (int off = 1; off < 64; off <<= 1) {
        int t = __shfl_up(v, off, 64);
        if (l >= off) v += t;
    }
    if (l < n) partials[l] = v - orig;
}

__global__ __launch_bounds__(256) void scan3(
    int* __restrict__ excl, const int* __restrict__ partials, int* __restrict__ cursor)
{
    int idx = blockIdx.x * 256 + threadIdx.x;
    if (idx < N_NODES) {
        int r = excl[idx] + partials[idx >> 10];
        excl[idx] = r;
        cursor[idx] = r;
    }
}

__global__ __launch_bounds__(256) void csr_fill(
    const int* __restrict__ ei, int* __restrict__ cursor, int* __restrict__ csr_src)
{
    int e = blockIdx.x * 256 + threadIdx.x;
    if (e < N_EDGES) {
        int s = ei[e];
        int d = ei[N_EDGES + e];
        int pos = atomicAdd(&cursor[d], 1);
        csr_src[pos] = s;
    }
}

// ===========================================================================
// Conversions
// ===========================================================================
// x fp32 -> bf16, 4 elems/thread; 6.4M elems = exactly 6250 blocks.
__global__ __launch_bounds__(256) void conv_x_bf(
    const float* __restrict__ x, u16* __restrict__ xb)
{
    int i = blockIdx.x * 256 + threadIdx.x;
    float4 v = ((const float4*)x)[i];
    ushort4 o;
    o.x = f2bf(v.x); o.y = f2bf(v.y); o.z = f2bf(v.z); o.w = f2bf(v.w);
    ((ushort4*)xb)[i] = o;
}

__device__ __forceinline__ void tr_one(
    const float* __restrict__ in, u16* __restrict__ out, int K, int N, int n)
{
    for (int k = threadIdx.x; k < K; k += 256) {
        float v = (n < N) ? in[(size_t)k * N + n] : 0.f;
        out[(size_t)n * K + k] = f2bf(v);
    }
}

// All 5 weight transposes in one dispatch. Grid ranges:
// [0,256) W1a; [256,512) W2a; [512,768) W1b; [768,1024) W2b; [1024,1152) Wlin.
__global__ __launch_bounds__(256) void transpose_all(
    const float* __restrict__ W1a, const float* __restrict__ W2a,
    const float* __restrict__ W1b, const float* __restrict__ W2b,
    const float* __restrict__ Wlin,
    u16* __restrict__ W1aT, u16* __restrict__ W2aT,
    u16* __restrict__ W1bT, u16* __restrict__ W2bT, u16* __restrict__ WlinT)
{
    int b = blockIdx.x;
    if (b < 256)       tr_one(W1a, W1aT, IN_CH, HID, b);
    else if (b < 512)  tr_one(W2a, W2aT, HID, HID, b - 256);
    else if (b < 768)  tr_one(W1b, W1bT, HID, HID, b - 512);
    else if (b < 1024) tr_one(W2b, W2bT, HID, HID, b - 768);
    else               tr_one(Wlin, WlinT, 2 * HID, OUT_CH, b - 1024);
}

// ===========================================================================
// Gather aggregation (bf16 in/out, fp32 accumulate), 4-deep unroll for MLP:
//   out[n] = feat[n] + sum_{e in CSR row n} feat[src[e]]
// One 64-lane wave per node.
// ===========================================================================
__global__ __launch_bounds__(256) void gather_agg_bf128(
    const u16* __restrict__ feat, const int* __restrict__ row_ptr,
    const int* __restrict__ row_end, const int* __restrict__ csr_src,
    u16* __restrict__ out)
{
    int node = (blockIdx.x * 256 + threadIdx.x) >> 6;
    int lane = threadIdx.x & 63;
    if (node >= N_NODES) return;
    ushort2 sv = ((const ushort2*)(feat + (size_t)node * IN_CH))[lane];
    float ax = bf2f(sv.x), ay = bf2f(sv.y);
    int j = row_ptr[node], e = row_end[node];
    for (; j + 4 <= e; j += 4) {
        int s0 = csr_src[j], s1 = csr_src[j + 1];
        int s2 = csr_src[j + 2], s3 = csr_src[j + 3];
        ushort2 v0 = ((const ushort2*)(feat + (size_t)s0 * IN_CH))[lane];
        ushort2 v1 = ((const ushort2*)(feat + (size_t)s1 * IN_CH))[lane];
        ushort2 v2 = ((const ushort2*)(feat + (size_t)s2 * IN_CH))[lane];
        ushort2 v3 = ((const ushort2*)(feat + (size_t)s3 * IN_CH))[lane];
        ax += (bf2f(v0.x) + bf2f(v1.x)) + (bf2f(v2.x) + bf2f(v3.x));
        ay += (bf2f(v0.y) + bf2f(v1.y)) + (bf2f(v2.y) + bf2f(v3.y));
    }
    for (; j < e; j++) {
        int sa = csr_src[j];
        ushort2 va = ((const ushort2*)(feat + (size_t)sa * IN_CH))[lane];
        ax += bf2f(va.x); ay += bf2f(va.y);
    }
    ushort2 o; o.x = f2bf(ax); o.y = f2bf(ay);
    ((ushort2*)(out + (size_t)node * IN_CH))[lane] = o;
}

__global__ __launch_bounds__(256) void gather_agg_bf256(
    const u16* __restrict__ feat, const int* __restrict__ row_ptr,
    const int* __restrict__ row_end, const int* __restrict__ csr_src,
    u16* __restrict__ out)
{
    int node = (blockIdx.x * 256 + threadIdx.x) >> 6;
    int lane = threadIdx.x & 63;
    if (node >= N_NODES) return;
    ushort4 sv = ((const ushort4*)(feat + (size_t)node * HID))[lane];
    float ax = bf2f(sv.x), ay = bf2f(sv.y), az = bf2f(sv.z), aw = bf2f(sv.w);
    int j = row_ptr[node], e = row_end[node];
    for (; j + 4 <= e; j += 4) {
        int s0 = csr_src[j], s1 = csr_src[j + 1];
        int s2 = csr_src[j + 2], s3 = csr_src[j + 3];
        ushort4 v0 = ((const ushort4*)(feat + (size_t)s0 * HID))[lane];
        ushort4 v1 = ((const ushort4*)(feat + (size_t)s1 * HID))[lane];
        ushort4 v2 = ((const ushort4*)(feat + (size_t)s2 * HID))[lane];
        ushort4 v3 = ((const ushort4*)(feat + (size_t)s3 * HID))[lane];
        ax += (bf2f(v0.x) + bf2f(v1.x)) + (bf2f(v2.x) + bf2f(v3.x));
        ay += (bf2f(v0.y) + bf2f(v1.y)) + (bf2f(v2.y) + bf2f(v3.y));
        az += (bf2f(v0.z) + bf2f(v1.z)) + (bf2f(v2.z) + bf2f(v3.z));
        aw += (bf2f(v0.w) + bf2f(v1.w)) + (bf2f(v2.w) + bf2f(v3.w));
    }
    for (; j < e; j++) {
        int sa = csr_src[j];
        ushort4 va = ((const ushort4*)(feat + (size_t)sa * HID))[lane];
        ax += bf2f(va.x); ay += bf2f(va.y); az += bf2f(va.z); aw += bf2f(va.w);
    }
    ushort4 o;
    o.x = f2bf(ax); o.y = f2bf(ay); o.z = f2bf(az); o.w = f2bf(aw);
    ((ushort4*)(out + (size_t)node * HID))[lane] = o;
}

// ===========================================================================
// bf16 MFMA GEMM (m97 structure): out = act(Aeff[M,K] @ BT^T + bias)
//   Aeff rows: A (k < Ksplit) / Acat (k >= Ksplit), both with row stride ldA.
//   BT is [Npad, K] bf16 row-major, Npad = 128*gridDim.x.
//   128x128 tile, BK=32, 4 waves x (64x64 via 4x4 MFMA tiles).
// fuseLS: epilogue computes log_softmax over cols 0..39 (requires gridDim.x==1,
//   Nreal=40) and writes fp32 to out[row*40+col].
// Fragment layouts (verified m89/m91): A[m=lane&15][k=(lane>>4)*8+j],
//   B[k=(lane>>4)*8+j][n=lane&15], C/D: col=lane&15, row=(lane>>4)*4+reg.
// ===========================================================================
__global__ __launch_bounds__(256, 2) void gemm_mfma(
    const u16* __restrict__ A, const u16* __restrict__ Acat, int Ksplit, int ldA,
    const u16* __restrict__ BT, const float* __restrict__ bias,
    void* __restrict__ out, int M, int Nreal, int K, int relu, int ldOut,
    int fuseLS)
{
    __shared__ u16 As[128 * 32];
    __shared__ u16 Bs[128 * 32];

    const int tid = threadIdx.x;
    const int lane = tid & 63;
    const int wid = tid >> 6;
    const int wm = wid >> 1, wn = wid & 1;
    const int row0 = blockIdx.y * 128;
    const int col0 = blockIdx.x * 128;

    f32x4 acc[4][4];
#pragma unroll
    for (int i = 0; i < 4; i++)
#pragma unroll
        for (int j = 0; j < 4; j++) acc[i][j] = (f32x4){0.f, 0.f, 0.f, 0.f};

    for (int kk = 0; kk < K; kk += 32) {
        const u16* Abase = (Acat != nullptr && kk >= Ksplit) ? Acat : A;
        const int kbase = (Acat != nullptr && kk >= Ksplit) ? (kk - Ksplit) : kk;
#pragma unroll
        for (int i = 0; i < 2; i++) {
            int chunk = i * 256 + tid;
            int r = chunk >> 2, c = chunk & 3;
            int grow = row0 + r; if (grow > M - 1) grow = M - 1;
            async_cp16(Abase + (size_t)grow * ldA + kbase + c * 8, As + chunk * 8);
        }
#pragma unroll
        for (int i = 0; i < 2; i++) {
            int chunk = i * 256 + tid;
            int r = chunk >> 2, c = chunk & 3;
            async_cp16(BT + (size_t)(col0 + r) * K + kk + c * 8, Bs + chunk * 8);
        }
        __syncthreads();

        const int koff = (lane >> 4) * 8;
        const int am = wm * 64 + (lane & 15);
        const int bn = wn * 64 + (lane & 15);
        bf16x8 af[4], bfr[4];
#pragma unroll
        for (int t = 0; t < 4; t++) {
            af[t]  = *(const bf16x8*)(As + (am + t * 16) * 32 + koff);
            bfr[t] = *(const bf16x8*)(Bs + (bn + t * 16) * 32 + koff);
        }
#pragma unroll
        for (int mt = 0; mt < 4; mt++)
#pragma unroll
            for (int nt = 0; nt < 4; nt++)
                acc[mt][nt] = __builtin_amdgcn_mfma_f32_16x16x32_bf16(
                    af[mt], bfr[nt], acc[mt][nt], 0, 0, 0);
        __syncthreads();
    }

    if (fuseLS) {
        // cols 0..39 live entirely in wn==0 waves: col = nt*16 + li, nt<=2.
        if (wn != 0) return;
        const int quad = lane >> 4, li = lane & 15;
        float b0 = bias[li];
        float b1 = bias[16 + li];
        float b2 = (li < 8) ? bias[32 + li] : 0.f;
        float* o = (float*)out;
#pragma unroll
        for (int mt = 0; mt < 4; mt++) {
#pragma unroll
            for (int reg = 0; reg < 4; reg++) {
                int row = row0 + wm * 64 + mt * 16 + quad * 4 + reg;
                float v0 = acc[mt][0][reg] + b0;
                float v1 = acc[mt][1][reg] + b1;
                float v2 = (li < 8) ? (acc[mt][2][reg] + b2) : -INFINITY;
                float m = fmaxf(fmaxf(v0, v1), v2);
#pragma unroll
                for (int off = 1; off < 16; off <<= 1)
                    m = fmaxf(m, __shfl_xor(m, off, 64));
                float s = expf(v0 - m) + expf(v1 - m)
                        + ((li < 8) ? expf(v2 - m) : 0.f);
#pragma unroll
                for (int off = 1; off < 16; off <<= 1)
                    s += __shfl_xor(s, off, 64);
                float lg = m + logf(s);
                if (row < M) {
                    o[(size_t)row * OUT_CH + li] = v0 - lg;
                    o[(size_t)row * OUT_CH + 16 + li] = v1 - lg;
                    if (li < 8) o[(size_t)row * OUT_CH + 32 + li] = v2 - lg;
                }
            }
        }
        return;
    }

    // ---- standard epilogue: bias + relu, bf16 out ----
#pragma unroll
    for (int nt = 0; nt < 4; nt++) {
        int col = col0 + wn * 64 + nt * 16 + (lane & 15);
        bool colOk = (col < Nreal);
        float bv = colOk ? bias[col] : 0.f;
#pragma unroll
        for (int mt = 0; mt < 4; mt++) {
            int rbase = row0 + wm * 64 + mt * 16 + ((lane >> 4) << 2);
#pragma unroll
            for (int reg = 0; reg < 4; reg++) {
                int row = rbase + reg;
                if (colOk && row < M) {
                    float v = acc[mt][nt][reg] + bv;
                    if (relu) v = fmaxf(v, 0.f);
                    ((u16*)out)[(size_t)row * ldOut + col] = f2bf(v);
                }
            }
        }
    }
}

// ---------------------------------------------------------------------------
extern "C" void kernel_launch(void* const* d_in, const int* in_sizes, int n_in,
                              void* d_out, int out_size, void* d_ws, size_t ws_size,
                              hipStream_t stream)
{
    const float* x    = (const float*)d_in[0];
    const int*   ei   = (const int*)d_in[1];
    const float* W1a  = (const float*)d_in[2];
    const float* b1a  = (const float*)d_in[3];
    const float* W2a  = (const float*)d_in[4];
    const float* b2a  = (const float*)d_in[5];
    const float* W1b  = (const float*)d_in[6];
    const float* b1b  = (const float*)d_in[7];
    const float* W2b  = (const float*)d_in[8];
    const float* b2b  = (const float*)d_in[9];
    const float* Wlin = (const float*)d_in[10];
    const float* blin = (const float*)d_in[11];
    float* out = (float*)d_out;

    // ---- workspace carve-up (regions of 50000*256 bf16 = 25.6 MB) ----
    const size_t R = (size_t)N_NODES * HID;
    u16* R0 = (u16*)d_ws;          // xbf -> t2
    u16* R1 = R0 + R;              // zA
    u16* R2 = R1 + R;              // t1 -> h2
    u16* R3 = R2 + R;              // h1 (live to end)
    u16* R4 = R3 + R;              // zB
    u16* xbf = R0;
    u16* zA  = R1;
    u16* t1  = R2;
    u16* h1  = R3;
    u16* zB  = R4;
    u16* t2  = R0;
    u16* h2  = R2;

    u16* wts = R4 + R;
    u16* W1aT = wts;                       // [256,128]
    u16* W2aT = W1aT + 256 * 128;          // [256,256]
    u16* W1bT = W2aT + 256 * 256;
    u16* W2bT = W1bT + 256 * 256;
    u16* WlinT = W2bT + 256 * 256;         // [128,512] (rows 40..127 zero)
    int* deg    = (int*)(WlinT + 128 * 512);
    int* rowp   = deg + N_NODES;
    int* cursor = rowp + N_NODES;
    int* part   = cursor + N_NODES;
    int* csr    = part + 64;               // [N_EDGES]

    dim3 blk(256);
    const int scanBlocks = (N_NODES + 1023) / 1024;  // 49
    const int edgeBlocks = (N_EDGES + 255) / 256;
    const int aggBlocks  = (N_NODES + 3) / 4;
    dim3 g2(2, (N_NODES + 127) / 128);
    dim3 g1(1, (N_NODES + 127) / 128);

    // ---- CSR build ----
    hipMemsetAsync(deg, 0, N_NODES * sizeof(int), stream);
    deg_count<<<edgeBlocks, blk, 0, stream>>>(ei, deg);
    scan1<<<scanBlocks, blk, 0, stream>>>(deg, rowp, part);
    scan2<<<1, 64, 0, stream>>>(part, scanBlocks);
    scan3<<<(N_NODES + 255) / 256, blk, 0, stream>>>(rowp, part, cursor);
    csr_fill<<<edgeBlocks, blk, 0, stream>>>(ei, cursor, csr);

    // ---- conversions ----
    conv_x_bf<<<(N_NODES * IN_CH / 4) / 256, blk, 0, stream>>>(x, xbf);
    transpose_all<<<1152, blk, 0, stream>>>(W1a, W2a, W1b, W2b, Wlin,
                                            W1aT, W2aT, W1bT, W2bT, WlinT);

    // ---- Layer a ----
    gather_agg_bf128<<<aggBlocks, blk, 0, stream>>>(xbf, rowp, cursor, csr, zA);
    gemm_mfma<<<g2, blk, 0, stream>>>(zA, nullptr, 0, IN_CH, W1aT, b1a,
                                      t1, N_NODES, HID, IN_CH, 1, HID, 0);
    gemm_mfma<<<g2, blk, 0, stream>>>(t1, nullptr, 0, HID, W2aT, b2a,
                                      h1, N_NODES, HID, HID, 1, HID, 0);

    // ---- Layer b ----
    gather_agg_bf256<<<aggBlocks, blk, 0, stream>>>(h1, rowp, cursor, csr, zB);
    gemm_mfma<<<g2, blk, 0, stream>>>(zB, nullptr, 0, HID, W1bT, b1b,
                                      t2, N_NODES, HID, HID, 1, HID, 0);
    gemm_mfma<<<g2, blk, 0, stream>>>(t2, nullptr, 0, HID, W2bT, b2b,
                                      h2, N_NODES, HID, HID, 1, HID, 0);

    // ---- Final linear on [h1 | h2] + fused log_softmax -> d_out ----
    gemm_mfma<<<g1, blk, 0, stream>>>(h1, h2, HID, HID, WlinT, blin,
                                      out, N_NODES, OUT_CH, 2 * HID, 0, OUT_CH, 1);
}